// Round 3
// baseline (4754.808 us; speedup 1.0000x reference)
//
#include <hip/hip_runtime.h>
#include <hip/hip_bf16.h>
#include <math.h>

// Problem constants (B, ST, TT, H, E, V, O) = (64, 1024, 256, 512, 512, 32, 31)
#define B_   64
#define ST_  1024
#define TT_  256
#define H_   512
#define E_   512
#define V_   32
#define O_   31
#define G3_  1536   // 3*H

// ---------------------------------------------------------------------------
// K0a: giV[v, n] = sum_k embed[v,k] * W_ih[n,k] + b_ih[n]   (32 x 1536)
// ---------------------------------------------------------------------------
__global__ __launch_bounds__(256) void k_giv(const float* __restrict__ embed,
                                             const float* __restrict__ W_ih,
                                             const float* __restrict__ b_ih,
                                             float* __restrict__ giV) {
    int idx = blockIdx.x * 256 + threadIdx.x;       // 0 .. 49151
    if (idx >= V_ * G3_) return;
    int v = idx / G3_, n = idx % G3_;
    const float4* e4 = (const float4*)(embed + v * E_);
    const float4* w4 = (const float4*)(W_ih + (size_t)n * E_);
    float acc = 0.f;
#pragma unroll 4
    for (int k = 0; k < E_ / 4; ++k) {
        float4 a = e4[k], b = w4[k];
        acc += a.x * b.x + a.y * b.y + a.z * b.z + a.w * b.w;
    }
    giV[idx] = acc + b_ih[n];
}

// ---------------------------------------------------------------------------
// K0b: transpose fc_W (31 x 1024) -> fc_Wt (1024 x 32), pad col 31 with 0
// ---------------------------------------------------------------------------
__global__ __launch_bounds__(256) void k_fcw_t(const float* __restrict__ fc_W,
                                               float* __restrict__ fc_Wt) {
    int idx = blockIdx.x * 256 + threadIdx.x;       // 0 .. 32767
    int k = idx >> 5, o = idx & 31;
    fc_Wt[idx] = (o < O_) ? fc_W[(size_t)o * 1024 + k] : 0.f;
}

// ---------------------------------------------------------------------------
// K1 v3: persistent GRU — ALL 256 steps in one dispatch.
// Grid = 512 blocks (bc=8 x jc=64) x 256 threads, __launch_bounds__(256,2)
// -> 2 blocks/CU co-resident (documented manual-coresidency pattern).
// Cross-block h traffic uses agent-scope atomics (sc-flagged loads/stores
// bypass the non-coherent per-XCD L2), so W_hh/giV stay L2-hot — no acquire
// invalidates. Inter-step sync: monotonic 2-level counter barrier
// (32 padded leaves -> root), tid0 spins with s_sleep.
// ---------------------------------------------------------------------------
__global__ __launch_bounds__(256, 2) void k_gru_all(const float* __restrict__ enc_last,
                                                    const float* __restrict__ giV,
                                                    const int* __restrict__ trg,
                                                    const float* __restrict__ W_hh,
                                                    const float* __restrict__ b_hh,
                                                    float* __restrict__ h_all,
                                                    unsigned* __restrict__ bar) {
    __shared__ float hs[8][520];                    // pad 512->520 floats
    int tid = threadIdx.x;
    int jc = blockIdx.x & 63, bc = blockIdx.x >> 6;
    int b0 = bc * 8;

    int bl = tid & 7;                               // batch within block
    int ks = (tid >> 3) & 3;                        // K-split id
    int jl = tid >> 5;                              // j within block
    int j  = jc * 8 + jl;
    int k0 = ks * 128;

    const float4* w0 = (const float4*)(W_hh + (size_t)(j         ) * H_ + k0);
    const float4* w1 = (const float4*)(W_hh + (size_t)(j +   H_  ) * H_ + k0);
    const float4* w2 = (const float4*)(W_hh + (size_t)(j + 2 * H_) * H_ + k0);
    const float4* h4 = (const float4*)&hs[bl][k0];
    float bh_r = b_hh[j], bh_z = b_hh[H_ + j], bh_n = b_hh[2 * H_ + j];

    unsigned* leaf = bar + (size_t)(blockIdx.x & 31) * 16;   // 64B-spaced leaves
    unsigned* root = bar + 32 * 16;

    for (int t = 0; t < TT_; ++t) {
        // ---- stage h_prev (8 rows x 512 f = 2048 ulongs) via agent-scope loads
        const float* hbase = (t == 0) ? enc_last : (h_all + (size_t)(t - 1) * H_);
        size_t rstride = (t == 0) ? (size_t)H_ : (size_t)TT_ * H_;
#pragma unroll
        for (int i = 0; i < 8; ++i) {
            int fi = tid + i * 256;                 // 0..2047
            int rb = fi >> 8, k2 = fi & 255;        // row 0..7, ulong 0..255
            const unsigned long long* p =
                (const unsigned long long*)(hbase + (size_t)(b0 + rb) * rstride) + k2;
            unsigned long long v = __hip_atomic_load(p, __ATOMIC_RELAXED,
                                                     __HIP_MEMORY_SCOPE_AGENT);
            *(unsigned long long*)&hs[rb][k2 * 2] = v;
        }
        __syncthreads();

        // ---- gate dots: this (b, j), K slice [k0, k0+128)
        float sr = 0.f, sz = 0.f, sn = 0.f;
#pragma unroll 8
        for (int k = 0; k < 32; ++k) {
            float4 hv = h4[k];
            float4 a = w0[k], c = w1[k], d = w2[k];
            sr += hv.x * a.x + hv.y * a.y + hv.z * a.z + hv.w * a.w;
            sz += hv.x * c.x + hv.y * c.y + hv.z * c.z + hv.w * c.w;
            sn += hv.x * d.x + hv.y * d.y + hv.z * d.z + hv.w * d.w;
        }
        sr += __shfl_xor(sr, 8);  sr += __shfl_xor(sr, 16);
        sz += __shfl_xor(sz, 8);  sz += __shfl_xor(sz, 16);
        sn += __shfl_xor(sn, 8);  sn += __shfl_xor(sn, 16);

        if (ks == 0) {
            int b = b0 + bl;
            int tok = trg[(size_t)b * TT_ + t];
            const float* gv = giV + (size_t)tok * G3_;
            float r = 1.f / (1.f + expf(-(gv[j] + sr + bh_r)));
            float z = 1.f / (1.f + expf(-(gv[H_ + j] + sz + bh_z)));
            float n = tanhf(gv[2 * H_ + j] + r * (sn + bh_n));
            float hp = hs[bl][j];
            float hv = (1.f - z) * n + z * hp;
            __hip_atomic_store(h_all + ((size_t)b * TT_ + t) * H_ + j, hv,
                               __ATOMIC_RELAXED, __HIP_MEMORY_SCOPE_AGENT);
        }

        __syncthreads();                            // compute + stores done blockwide
        if (t + 1 < TT_) {
            if (tid == 0) {
                __builtin_amdgcn_fence(__ATOMIC_RELEASE, "agent");
                unsigned prev = __hip_atomic_fetch_add(leaf, 1u, __ATOMIC_RELAXED,
                                                       __HIP_MEMORY_SCOPE_AGENT);
                if (prev == 16u * (unsigned)(t + 1) - 1u)       // last of 16 at this leaf
                    __hip_atomic_fetch_add(root, 1u, __ATOMIC_RELAXED,
                                           __HIP_MEMORY_SCOPE_AGENT);
                unsigned target = 32u * (unsigned)(t + 1);
                while (__hip_atomic_load(root, __ATOMIC_RELAXED,
                                         __HIP_MEMORY_SCOPE_AGENT) < target)
                    __builtin_amdgcn_s_sleep(8);
                asm volatile("" ::: "memory");
            }
            __syncthreads();
        }
    }
}

// FMA micro-kernel helper for the 4x4 register tiles
#define FMA16(a, bb)                                                     \
    acc[0][0] = fmaf(a.x, bb.x, acc[0][0]);                              \
    acc[0][1] = fmaf(a.x, bb.y, acc[0][1]);                              \
    acc[0][2] = fmaf(a.x, bb.z, acc[0][2]);                              \
    acc[0][3] = fmaf(a.x, bb.w, acc[0][3]);                              \
    acc[1][0] = fmaf(a.y, bb.x, acc[1][0]);                              \
    acc[1][1] = fmaf(a.y, bb.y, acc[1][1]);                              \
    acc[1][2] = fmaf(a.y, bb.z, acc[1][2]);                              \
    acc[1][3] = fmaf(a.y, bb.w, acc[1][3]);                              \
    acc[2][0] = fmaf(a.z, bb.x, acc[2][0]);                              \
    acc[2][1] = fmaf(a.z, bb.y, acc[2][1]);                              \
    acc[2][2] = fmaf(a.z, bb.z, acc[2][2]);                              \
    acc[2][3] = fmaf(a.z, bb.w, acc[2][3]);                              \
    acc[3][0] = fmaf(a.w, bb.x, acc[3][0]);                              \
    acc[3][1] = fmaf(a.w, bb.y, acc[3][1]);                              \
    acc[3][2] = fmaf(a.w, bb.z, acc[3][2]);                              \
    acc[3][3] = fmaf(a.w, bb.w, acc[3][3]);

// ---------------------------------------------------------------------------
// K2: scores[b, t, s] = sum_k h_all[b,t,k] * enc[b,s,k]   (NT GEMM per batch)
// ---------------------------------------------------------------------------
__global__ __launch_bounds__(256) void k_scores(const float* __restrict__ h_all,
                                                const float* __restrict__ enc,
                                                float* __restrict__ wgt) {
    __shared__ float As[16][68];
    __shared__ float Bs[16][68];
    int b  = blockIdx.z;
    int m0 = blockIdx.y * 64, n0 = blockIdx.x * 64;
    int tid = threadIdx.x;
    int tx = tid & 15, ty = tid >> 4;
    int lr = tid >> 2, lk = (tid & 3) * 4;

    const float* Abase = h_all + (size_t)b * TT_ * H_ + (size_t)(m0 + lr) * H_ + lk;
    const float* Bbase = enc   + (size_t)b * ST_ * H_ + (size_t)(n0 + lr) * H_ + lk;

    float acc[4][4] = {};
    for (int k0 = 0; k0 < H_; k0 += 16) {
        float4 av = *(const float4*)(Abase + k0);
        float4 bv = *(const float4*)(Bbase + k0);
        __syncthreads();
        As[lk + 0][lr] = av.x; As[lk + 1][lr] = av.y;
        As[lk + 2][lr] = av.z; As[lk + 3][lr] = av.w;
        Bs[lk + 0][lr] = bv.x; Bs[lk + 1][lr] = bv.y;
        Bs[lk + 2][lr] = bv.z; Bs[lk + 3][lr] = bv.w;
        __syncthreads();
#pragma unroll
        for (int kk = 0; kk < 16; ++kk) {
            float4 a  = *(const float4*)&As[kk][ty * 4];
            float4 bb = *(const float4*)&Bs[kk][tx * 4];
            FMA16(a, bb)
        }
    }
#pragma unroll
    for (int i = 0; i < 4; ++i)
#pragma unroll
        for (int jj = 0; jj < 4; ++jj)
            wgt[(size_t)b * TT_ * ST_ + (size_t)(m0 + ty * 4 + i) * ST_ + (n0 + tx * 4 + jj)] = acc[i][jj];
}

// ---------------------------------------------------------------------------
// K3: masked softmax over s (row length 1024). One block per (b, t) row.
// ---------------------------------------------------------------------------
__global__ __launch_bounds__(256) void k_softmax(float* __restrict__ wgt,
                                                 const int* __restrict__ source_len) {
    __shared__ float red[8];
    int row = blockIdx.x;            // b*TT + t
    int b = row >> 8;
    int slen = source_len[b];
    float* W = wgt + (size_t)row * ST_;
    int tid = threadIdx.x;

    float v[4];
    float mx = -3.0e38f;
#pragma unroll
    for (int i = 0; i < 4; ++i) {
        int s = tid + i * 256;
        v[i] = (s < slen) ? W[s] : -1e9f;
        mx = fmaxf(mx, v[i]);
    }
#pragma unroll
    for (int off = 32; off; off >>= 1) mx = fmaxf(mx, __shfl_xor(mx, off));
    int wv = tid >> 6;
    if ((tid & 63) == 0) red[wv] = mx;
    __syncthreads();
    mx = fmaxf(fmaxf(red[0], red[1]), fmaxf(red[2], red[3]));

    float sm = 0.f;
#pragma unroll
    for (int i = 0; i < 4; ++i) {
        v[i] = expf(v[i] - mx);
        sm += v[i];
    }
#pragma unroll
    for (int off = 32; off; off >>= 1) sm += __shfl_xor(sm, off);
    if ((tid & 63) == 0) red[4 + wv] = sm;
    __syncthreads();
    sm = red[4] + red[5] + red[6] + red[7];
    float inv = 1.f / sm;
#pragma unroll
    for (int i = 0; i < 4; ++i)
        W[tid + i * 256] = v[i] * inv;
}

// ---------------------------------------------------------------------------
// K4: ctx[b, t, n] = sum_s wgt[b,t,s] * enc[b,s,n]   (NN GEMM per batch)
// ---------------------------------------------------------------------------
__global__ __launch_bounds__(256) void k_ctx(const float* __restrict__ wgt,
                                             const float* __restrict__ enc,
                                             float* __restrict__ ctx) {
    __shared__ float As[16][68];
    __shared__ float Bs[16][68];
    int b  = blockIdx.z;
    int m0 = blockIdx.y * 64, n0 = blockIdx.x * 64;
    int tid = threadIdx.x;
    int tx = tid & 15, ty = tid >> 4;
    int lr = tid >> 2, lk = (tid & 3) * 4;     // A-tile load mapping
    int bk = tid >> 4, bn = (tid & 15) * 4;    // B-tile load mapping

    const float* Abase = wgt + (size_t)b * TT_ * ST_ + (size_t)(m0 + lr) * ST_ + lk;
    const float* Bbase = enc + (size_t)b * ST_ * H_ + n0 + bn;

    float acc[4][4] = {};
    for (int k0 = 0; k0 < ST_; k0 += 16) {
        float4 av = *(const float4*)(Abase + k0);
        float4 bv = *(const float4*)(Bbase + (size_t)(k0 + bk) * H_);
        __syncthreads();
        As[lk + 0][lr] = av.x; As[lk + 1][lr] = av.y;
        As[lk + 2][lr] = av.z; As[lk + 3][lr] = av.w;
        *(float4*)&Bs[bk][bn] = bv;
        __syncthreads();
#pragma unroll
        for (int kk = 0; kk < 16; ++kk) {
            float4 a  = *(const float4*)&As[kk][ty * 4];
            float4 bb = *(const float4*)&Bs[kk][tx * 4];
            FMA16(a, bb)
        }
    }
#pragma unroll
    for (int i = 0; i < 4; ++i)
#pragma unroll
        for (int jj = 0; jj < 4; ++jj)
            ctx[(size_t)b * TT_ * H_ + (size_t)(m0 + ty * 4 + i) * H_ + (n0 + tx * 4 + jj)] = acc[i][jj];
}

// ---------------------------------------------------------------------------
// K5: out[b,t,o] = (t < trg_len[b]) ? [h|ctx] . fc_W[o] + fc_b[o] : 0
// ---------------------------------------------------------------------------
__global__ __launch_bounds__(256) void k_out(const float* __restrict__ h_all,
                                             const float* __restrict__ ctx,
                                             const float* __restrict__ fc_Wt,
                                             const float* __restrict__ fc_b,
                                             const int* __restrict__ trg_len,
                                             float* __restrict__ out) {
    int tid = threadIdx.x;
    int o = tid & 31;
    int m = blockIdx.x * 8 + (tid >> 5);     // b*TT + t
    int b = m >> 8, t = m & 255;
    const float* xh = h_all + (size_t)m * H_;
    const float* xc = ctx + (size_t)m * H_;
    float acc = (o < O_) ? fc_b[o] : 0.f;
#pragma unroll 4
    for (int k = 0; k < H_; ++k) acc = fmaf(xh[k], fc_Wt[k * 32 + o], acc);
#pragma unroll 4
    for (int k = 0; k < H_; ++k) acc = fmaf(xc[k], fc_Wt[(H_ + k) * 32 + o], acc);
    if (o < O_) {
        float val = (t < trg_len[b]) ? acc : 0.0f;
        out[(size_t)m * O_ + o] = val;
    }
}

// ---------------------------------------------------------------------------
extern "C" void kernel_launch(void* const* d_in, const int* in_sizes, int n_in,
                              void* d_out, int out_size, void* d_ws, size_t ws_size,
                              hipStream_t stream) {
    const int*   trg      = (const int*)d_in[0];
    const int*   trg_len  = (const int*)d_in[1];
    const int*   src_len  = (const int*)d_in[2];
    const float* enc      = (const float*)d_in[3];
    const float* enc_last = (const float*)d_in[4];
    const float* embed    = (const float*)d_in[5];
    const float* W_ih     = (const float*)d_in[6];
    const float* W_hh     = (const float*)d_in[7];
    const float* b_ih     = (const float*)d_in[8];
    const float* b_hh     = (const float*)d_in[9];
    const float* fc_W     = (const float*)d_in[10];
    const float* fc_b     = (const float*)d_in[11];
    float* out = (float*)d_out;

    char* ws = (char*)d_ws;
    float*    giV   = (float*)ws;    ws += (size_t)V_ * G3_ * 4;        // 192 KB
    float*    fc_Wt = (float*)ws;    ws += (size_t)1024 * 32 * 4;       // 128 KB
    float*    h_all = (float*)ws;    ws += (size_t)B_ * TT_ * H_ * 4;   // 32 MB
    float*    wgt   = (float*)ws;    ws += (size_t)B_ * TT_ * ST_ * 4;  // 64 MB
    float*    ctx   = (float*)ws;    ws += (size_t)B_ * TT_ * H_ * 4;   // 32 MB
    unsigned* bar   = (unsigned*)ws; ws += 4096;                        // barrier tree

    hipMemsetAsync(bar, 0, 4096, stream);
    k_giv<<<192, 256, 0, stream>>>(embed, W_ih, b_ih, giV);
    k_fcw_t<<<128, 256, 0, stream>>>(fc_W, fc_Wt);

    k_gru_all<<<512, 256, 0, stream>>>(enc_last, giV, trg, W_hh, b_hh, h_all, bar);

    k_scores<<<dim3(ST_ / 64, TT_ / 64, B_), 256, 0, stream>>>(h_all, enc, wgt);
    k_softmax<<<B_ * TT_, 256, 0, stream>>>(wgt, src_len);
    k_ctx<<<dim3(H_ / 64, TT_ / 64, B_), 256, 0, stream>>>(wgt, enc, ctx);
    k_out<<<B_ * TT_ / 8, 256, 0, stream>>>(h_all, ctx, fc_Wt, fc_b, trg_len, out);
}

// Round 5
// 4674.635 us; speedup vs baseline: 1.0172x; 1.0172x over previous
//
#include <hip/hip_runtime.h>
#include <hip/hip_bf16.h>
#include <math.h>

// Problem constants (B, ST, TT, H, E, V, O) = (64, 1024, 256, 512, 512, 32, 31)
#define B_   64
#define ST_  1024
#define TT_  256
#define H_   512
#define E_   512
#define V_   32
#define O_   31
#define G3_  1536   // 3*H

// ---------------------------------------------------------------------------
// K0a: giV[v, n] = sum_k embed[v,k] * W_ih[n,k] + b_ih[n]   (32 x 1536)
// ---------------------------------------------------------------------------
__global__ __launch_bounds__(256) void k_giv(const float* __restrict__ embed,
                                             const float* __restrict__ W_ih,
                                             const float* __restrict__ b_ih,
                                             float* __restrict__ giV) {
    int idx = blockIdx.x * 256 + threadIdx.x;       // 0 .. 49151
    if (idx >= V_ * G3_) return;
    int v = idx / G3_, n = idx % G3_;
    const float4* e4 = (const float4*)(embed + v * E_);
    const float4* w4 = (const float4*)(W_ih + (size_t)n * E_);
    float acc = 0.f;
#pragma unroll 4
    for (int k = 0; k < E_ / 4; ++k) {
        float4 a = e4[k], b = w4[k];
        acc += a.x * b.x + a.y * b.y + a.z * b.z + a.w * b.w;
    }
    giV[idx] = acc + b_ih[n];
}

// ---------------------------------------------------------------------------
// K0b: transpose fc_W (31 x 1024) -> fc_Wt (1024 x 32), pad col 31 with 0
// ---------------------------------------------------------------------------
__global__ __launch_bounds__(256) void k_fcw_t(const float* __restrict__ fc_W,
                                               float* __restrict__ fc_Wt) {
    int idx = blockIdx.x * 256 + threadIdx.x;       // 0 .. 32767
    int k = idx >> 5, o = idx & 31;
    fc_Wt[idx] = (o < O_) ? fc_W[(size_t)o * 1024 + k] : 0.f;
}

// ---------------------------------------------------------------------------
// K1 v5: persistent GRU, all 256 steps in one dispatch.
// Grid = 512 blocks (bc=8 x jc=64) x 256 threads, 2 blocks/CU (co-resident).
// Block (bc,jc): b in [bc*8,+8), j in [jc*8,+8); consumes h only from its own
// bc-group -> per-group barrier over 64 blocks.
//
// PUBLISH PROTOCOL (the round-4 bug fix): h values are published with
// no-return agent-scope atomic_exchange. Agent-scope RMWs are PERFORMED AT
// THE LLC (the cross-XCD coherence point) and vmcnt holds until the LLC ack,
// so once __syncthreads' vmcnt(0) drain completes, the data IS in the LLC.
// (Round 4 used a plain agent store: vmcnt retirement there does NOT imply
// LLC visibility -> intermittent post-timing divergence. Round 3's release
// fence fixed that via buffer_wbl2 — a full per-block L2 writeback per step,
// ~13 us/step of sync. The swap gives the ordering without the wbl2.)
// tid0 then bumps the group counter (RMW at LLC, control-dependent on the
// barrier so it cannot be hoisted above the drain); consumers spin on a
// relaxed sc1 load and stage h with relaxed sc1 loads that read the LLC
// (proved stale-free by round 3, which never issued an acquire-invalidate).
// ---------------------------------------------------------------------------
__global__ __launch_bounds__(256, 2) void k_gru_all(const float* __restrict__ enc_last,
                                                    const float* __restrict__ giV,
                                                    const int* __restrict__ trg,
                                                    const float* __restrict__ W_hh,
                                                    const float* __restrict__ b_hh,
                                                    float* __restrict__ h_all,
                                                    unsigned* __restrict__ bar) {
    __shared__ float hs[8][520];                    // pad 512->520 floats
    int tid = threadIdx.x;
    int jc = blockIdx.x & 63, bc = blockIdx.x >> 6;
    int b0 = bc * 8;

    int bl = tid & 7;                               // batch within block
    int ks = (tid >> 3) & 3;                        // K-split id
    int jl = tid >> 5;                              // j within block
    int j  = jc * 8 + jl;
    int k0 = ks * 128;

    const float4* w0 = (const float4*)(W_hh + (size_t)(j         ) * H_ + k0);
    const float4* w1 = (const float4*)(W_hh + (size_t)(j +   H_  ) * H_ + k0);
    const float4* w2 = (const float4*)(W_hh + (size_t)(j + 2 * H_) * H_ + k0);
    const float4* h4 = (const float4*)&hs[bl][k0];
    float bh_r = b_hh[j], bh_z = b_hh[H_ + j], bh_n = b_hh[2 * H_ + j];

    unsigned* gbar = bar + (size_t)bc * 64;         // per-group counter, 256B apart

    for (int t = 0; t < TT_; ++t) {
        // ---- stage h_prev (8 rows x 512 f = 2048 ulongs) via agent-scope loads
        const float* hbase = (t == 0) ? enc_last : (h_all + (size_t)(t - 1) * H_);
        size_t rstride = (t == 0) ? (size_t)H_ : (size_t)TT_ * H_;
#pragma unroll
        for (int i = 0; i < 8; ++i) {
            int fi = tid + i * 256;                 // 0..2047
            int rb = fi >> 8, k2 = fi & 255;        // row 0..7, ulong 0..255
            const unsigned long long* p =
                (const unsigned long long*)(hbase + (size_t)(b0 + rb) * rstride) + k2;
            unsigned long long v = __hip_atomic_load(p, __ATOMIC_RELAXED,
                                                     __HIP_MEMORY_SCOPE_AGENT);
            *(unsigned long long*)&hs[rb][k2 * 2] = v;
        }
        __syncthreads();

        // ---- gate dots: this (b, j), K slice [k0, k0+128)
        float sr = 0.f, sz = 0.f, sn = 0.f;
#pragma unroll 8
        for (int k = 0; k < 32; ++k) {
            float4 hv = h4[k];
            float4 a = w0[k], c = w1[k], d = w2[k];
            sr += hv.x * a.x + hv.y * a.y + hv.z * a.z + hv.w * a.w;
            sz += hv.x * c.x + hv.y * c.y + hv.z * c.z + hv.w * c.w;
            sn += hv.x * d.x + hv.y * d.y + hv.z * d.z + hv.w * d.w;
        }
        sr += __shfl_xor(sr, 8);  sr += __shfl_xor(sr, 16);
        sz += __shfl_xor(sz, 8);  sz += __shfl_xor(sz, 16);
        sn += __shfl_xor(sn, 8);  sn += __shfl_xor(sn, 16);

        if (ks == 0) {
            int b = b0 + bl;
            int tok = trg[(size_t)b * TT_ + t];
            const float* gv = giV + (size_t)tok * G3_;
            float r = 1.f / (1.f + expf(-(gv[j] + sr + bh_r)));
            float z = 1.f / (1.f + expf(-(gv[H_ + j] + sz + bh_z)));
            float n = tanhf(gv[2 * H_ + j] + r * (sn + bh_n));
            float hp = hs[bl][j];
            float hv = (1.f - z) * n + z * hp;
            // publish at the LLC: no-return agent-scope RMW (see header comment)
            (void)__hip_atomic_exchange(h_all + ((size_t)b * TT_ + t) * H_ + j, hv,
                                        __ATOMIC_RELAXED, __HIP_MEMORY_SCOPE_AGENT);
        }

        // vmcnt(0) drain before s_barrier -> all swaps acked BY THE LLC.
        __syncthreads();
        if (t + 1 < TT_) {
            if (tid == 0) {
                __hip_atomic_fetch_add(gbar, 1u, __ATOMIC_RELAXED,
                                       __HIP_MEMORY_SCOPE_AGENT);
                unsigned target = 64u * (unsigned)(t + 1);
                while (__hip_atomic_load(gbar, __ATOMIC_RELAXED,
                                         __HIP_MEMORY_SCOPE_AGENT) < target)
                    __builtin_amdgcn_s_sleep(2);
                asm volatile("" ::: "memory");
            }
            __syncthreads();
        }
    }
}

// FMA micro-kernel helper for the 4x4 register tiles
#define FMA16(a, bb)                                                     \
    acc[0][0] = fmaf(a.x, bb.x, acc[0][0]);                              \
    acc[0][1] = fmaf(a.x, bb.y, acc[0][1]);                              \
    acc[0][2] = fmaf(a.x, bb.z, acc[0][2]);                              \
    acc[0][3] = fmaf(a.x, bb.w, acc[0][3]);                              \
    acc[1][0] = fmaf(a.y, bb.x, acc[1][0]);                              \
    acc[1][1] = fmaf(a.y, bb.y, acc[1][1]);                              \
    acc[1][2] = fmaf(a.y, bb.z, acc[1][2]);                              \
    acc[1][3] = fmaf(a.y, bb.w, acc[1][3]);                              \
    acc[2][0] = fmaf(a.z, bb.x, acc[2][0]);                              \
    acc[2][1] = fmaf(a.z, bb.y, acc[2][1]);                              \
    acc[2][2] = fmaf(a.z, bb.z, acc[2][2]);                              \
    acc[2][3] = fmaf(a.z, bb.w, acc[2][3]);                              \
    acc[3][0] = fmaf(a.w, bb.x, acc[3][0]);                              \
    acc[3][1] = fmaf(a.w, bb.y, acc[3][1]);                              \
    acc[3][2] = fmaf(a.w, bb.z, acc[3][2]);                              \
    acc[3][3] = fmaf(a.w, bb.w, acc[3][3]);

// ---------------------------------------------------------------------------
// K2: scores[b, t, s] = sum_k h_all[b,t,k] * enc[b,s,k]   (NT GEMM per batch)
// ---------------------------------------------------------------------------
__global__ __launch_bounds__(256) void k_scores(const float* __restrict__ h_all,
                                                const float* __restrict__ enc,
                                                float* __restrict__ wgt) {
    __shared__ float As[16][68];
    __shared__ float Bs[16][68];
    int b  = blockIdx.z;
    int m0 = blockIdx.y * 64, n0 = blockIdx.x * 64;
    int tid = threadIdx.x;
    int tx = tid & 15, ty = tid >> 4;
    int lr = tid >> 2, lk = (tid & 3) * 4;

    const float* Abase = h_all + (size_t)b * TT_ * H_ + (size_t)(m0 + lr) * H_ + lk;
    const float* Bbase = enc   + (size_t)b * ST_ * H_ + (size_t)(n0 + lr) * H_ + lk;

    float acc[4][4] = {};
    for (int k0 = 0; k0 < H_; k0 += 16) {
        float4 av = *(const float4*)(Abase + k0);
        float4 bv = *(const float4*)(Bbase + k0);
        __syncthreads();
        As[lk + 0][lr] = av.x; As[lk + 1][lr] = av.y;
        As[lk + 2][lr] = av.z; As[lk + 3][lr] = av.w;
        Bs[lk + 0][lr] = bv.x; Bs[lk + 1][lr] = bv.y;
        Bs[lk + 2][lr] = bv.z; Bs[lk + 3][lr] = bv.w;
        __syncthreads();
#pragma unroll
        for (int kk = 0; kk < 16; ++kk) {
            float4 a  = *(const float4*)&As[kk][ty * 4];
            float4 bb = *(const float4*)&Bs[kk][tx * 4];
            FMA16(a, bb)
        }
    }
#pragma unroll
    for (int i = 0; i < 4; ++i)
#pragma unroll
        for (int jj = 0; jj < 4; ++jj)
            wgt[(size_t)b * TT_ * ST_ + (size_t)(m0 + ty * 4 + i) * ST_ + (n0 + tx * 4 + jj)] = acc[i][jj];
}

// ---------------------------------------------------------------------------
// K3: masked softmax over s (row length 1024). One block per (b, t) row.
// ---------------------------------------------------------------------------
__global__ __launch_bounds__(256) void k_softmax(float* __restrict__ wgt,
                                                 const int* __restrict__ source_len) {
    __shared__ float red[8];
    int row = blockIdx.x;            // b*TT + t
    int b = row >> 8;
    int slen = source_len[b];
    float* W = wgt + (size_t)row * ST_;
    int tid = threadIdx.x;

    float v[4];
    float mx = -3.0e38f;
#pragma unroll
    for (int i = 0; i < 4; ++i) {
        int s = tid + i * 256;
        v[i] = (s < slen) ? W[s] : -1e9f;
        mx = fmaxf(mx, v[i]);
    }
#pragma unroll
    for (int off = 32; off; off >>= 1) mx = fmaxf(mx, __shfl_xor(mx, off));
    int wv = tid >> 6;
    if ((tid & 63) == 0) red[wv] = mx;
    __syncthreads();
    mx = fmaxf(fmaxf(red[0], red[1]), fmaxf(red[2], red[3]));

    float sm = 0.f;
#pragma unroll
    for (int i = 0; i < 4; ++i) {
        v[i] = expf(v[i] - mx);
        sm += v[i];
    }
#pragma unroll
    for (int off = 32; off; off >>= 1) sm += __shfl_xor(sm, off);
    if ((tid & 63) == 0) red[4 + wv] = sm;
    __syncthreads();
    sm = red[4] + red[5] + red[6] + red[7];
    float inv = 1.f / sm;
#pragma unroll
    for (int i = 0; i < 4; ++i)
        W[tid + i * 256] = v[i] * inv;
}

// ---------------------------------------------------------------------------
// K4: ctx[b, t, n] = sum_s wgt[b,t,s] * enc[b,s,n]   (NN GEMM per batch)
// ---------------------------------------------------------------------------
__global__ __launch_bounds__(256) void k_ctx(const float* __restrict__ wgt,
                                             const float* __restrict__ enc,
                                             float* __restrict__ ctx) {
    __shared__ float As[16][68];
    __shared__ float Bs[16][68];
    int b  = blockIdx.z;
    int m0 = blockIdx.y * 64, n0 = blockIdx.x * 64;
    int tid = threadIdx.x;
    int tx = tid & 15, ty = tid >> 4;
    int lr = tid >> 2, lk = (tid & 3) * 4;     // A-tile load mapping
    int bk = tid >> 4, bn = (tid & 15) * 4;    // B-tile load mapping

    const float* Abase = wgt + (size_t)b * TT_ * ST_ + (size_t)(m0 + lr) * ST_ + lk;
    const float* Bbase = enc + (size_t)b * ST_ * H_ + n0 + bn;

    float acc[4][4] = {};
    for (int k0 = 0; k0 < ST_; k0 += 16) {
        float4 av = *(const float4*)(Abase + k0);
        float4 bv = *(const float4*)(Bbase + (size_t)(k0 + bk) * H_);
        __syncthreads();
        As[lk + 0][lr] = av.x; As[lk + 1][lr] = av.y;
        As[lk + 2][lr] = av.z; As[lk + 3][lr] = av.w;
        *(float4*)&Bs[bk][bn] = bv;
        __syncthreads();
#pragma unroll
        for (int kk = 0; kk < 16; ++kk) {
            float4 a  = *(const float4*)&As[kk][ty * 4];
            float4 bb = *(const float4*)&Bs[kk][tx * 4];
            FMA16(a, bb)
        }
    }
#pragma unroll
    for (int i = 0; i < 4; ++i)
#pragma unroll
        for (int jj = 0; jj < 4; ++jj)
            ctx[(size_t)b * TT_ * H_ + (size_t)(m0 + ty * 4 + i) * H_ + (n0 + tx * 4 + jj)] = acc[i][jj];
}

// ---------------------------------------------------------------------------
// K5: out[b,t,o] = (t < trg_len[b]) ? [h|ctx] . fc_W[o] + fc_b[o] : 0
// ---------------------------------------------------------------------------
__global__ __launch_bounds__(256) void k_out(const float* __restrict__ h_all,
                                             const float* __restrict__ ctx,
                                             const float* __restrict__ fc_Wt,
                                             const float* __restrict__ fc_b,
                                             const int* __restrict__ trg_len,
                                             float* __restrict__ out) {
    int tid = threadIdx.x;
    int o = tid & 31;
    int m = blockIdx.x * 8 + (tid >> 5);     // b*TT + t
    int b = m >> 8, t = m & 255;
    const float* xh = h_all + (size_t)m * H_;
    const float* xc = ctx + (size_t)m * H_;
    float acc = (o < O_) ? fc_b[o] : 0.f;
#pragma unroll 4
    for (int k = 0; k < H_; ++k) acc = fmaf(xh[k], fc_Wt[k * 32 + o], acc);
#pragma unroll 4
    for (int k = 0; k < H_; ++k) acc = fmaf(xc[k], fc_Wt[(H_ + k) * 32 + o], acc);
    if (o < O_) {
        float val = (t < trg_len[b]) ? acc : 0.0f;
        out[(size_t)m * O_ + o] = val;
    }
}

// ---------------------------------------------------------------------------
extern "C" void kernel_launch(void* const* d_in, const int* in_sizes, int n_in,
                              void* d_out, int out_size, void* d_ws, size_t ws_size,
                              hipStream_t stream) {
    const int*   trg      = (const int*)d_in[0];
    const int*   trg_len  = (const int*)d_in[1];
    const int*   src_len  = (const int*)d_in[2];
    const float* enc      = (const float*)d_in[3];
    const float* enc_last = (const float*)d_in[4];
    const float* embed    = (const float*)d_in[5];
    const float* W_ih     = (const float*)d_in[6];
    const float* W_hh     = (const float*)d_in[7];
    const float* b_ih     = (const float*)d_in[8];
    const float* b_hh     = (const float*)d_in[9];
    const float* fc_W     = (const float*)d_in[10];
    const float* fc_b     = (const float*)d_in[11];
    float* out = (float*)d_out;

    char* ws = (char*)d_ws;
    float*    giV   = (float*)ws;    ws += (size_t)V_ * G3_ * 4;        // 192 KB
    float*    fc_Wt = (float*)ws;    ws += (size_t)1024 * 32 * 4;       // 128 KB
    float*    h_all = (float*)ws;    ws += (size_t)B_ * TT_ * H_ * 4;   // 32 MB
    float*    wgt   = (float*)ws;    ws += (size_t)B_ * TT_ * ST_ * 4;  // 64 MB
    float*    ctx   = (float*)ws;    ws += (size_t)B_ * TT_ * H_ * 4;   // 32 MB
    unsigned* bar   = (unsigned*)ws; ws += 4096;                        // barrier counters

    hipMemsetAsync(bar, 0, 4096, stream);
    k_giv<<<192, 256, 0, stream>>>(embed, W_ih, b_ih, giV);
    k_fcw_t<<<128, 256, 0, stream>>>(fc_W, fc_Wt);

    k_gru_all<<<512, 256, 0, stream>>>(enc_last, giV, trg, W_hh, b_hh, h_all, bar);

    k_scores<<<dim3(ST_ / 64, TT_ / 64, B_), 256, 0, stream>>>(h_all, enc, wgt);
    k_softmax<<<B_ * TT_, 256, 0, stream>>>(wgt, src_len);
    k_ctx<<<dim3(H_ / 64, TT_ / 64, B_), 256, 0, stream>>>(wgt, enc, ctx);
    k_out<<<B_ * TT_ / 8, 256, 0, stream>>>(h_all, ctx, fc_Wt, fc_b, trg_len, out);
}